// Round 4
// baseline (579.520 us; speedup 1.0000x reference)
//
#include <hip/hip_runtime.h>

#define NSEG 512
#define NSPLIT 16

typedef __attribute__((ext_vector_type(8))) short short8;
typedef __attribute__((ext_vector_type(4))) float floatx4;

// ws layout (bytes), all 16B-aligned, total 409920 <= proven 446784
#define WS_WAT   0        // short [256][32]   WA^T
#define WS_WBT2  16384    // short [256][64]   WB^T (K padded 48->64 w/ zeros)
#define WS_W2GA  49152    // short [256][256]  (gA*Wback)^T
#define WS_W2GB  180224   // short [256][256]  (gB*Wback)^T
#define WS_C1A   311296   // float[8][256] partials: gA . Wback[:,n] (k-chunk j)
#define WS_C2A   319488   // float[8][256] partials: betaA . Wback[:,n] (+bback in j=0)
#define WS_C1B   327680   // float[8][256]
#define WS_C2B   335872   // float[8][256]
#define WS_INVA  344064   // float[32]  1/stdA
#define WS_INVB  344192   // float[48]  1/stdB
#define WS_VPART 344384   // float [NSPLIT][NSEG]
#define WS_CPART 377152   // float [NSPLIT][NSEG]
// end 409920

__device__ __forceinline__ short f2bf(float f) {  // RNE
  unsigned u = __builtin_bit_cast(unsigned, f);
  u += 0x7FFFu + ((u >> 16) & 1u);
  return (short)(u >> 16);
}

__global__ void prep_kernel(const float* __restrict__ WA, const float* __restrict__ WB,
                            const float* __restrict__ Wback,
                            const float* __restrict__ gA, const float* __restrict__ betaA,
                            const float* __restrict__ gB, const float* __restrict__ betaB,
                            const float* __restrict__ bback,
                            const float* __restrict__ sA, const float* __restrict__ sB,
                            char* __restrict__ ws) {
  short* waT  = (short*)(ws + WS_WAT);
  short* wbT2 = (short*)(ws + WS_WBT2);
  short* w2gA = (short*)(ws + WS_W2GA);
  short* w2gB = (short*)(ws + WS_W2GB);
  float* c1A = (float*)(ws + WS_C1A);
  float* c2A = (float*)(ws + WS_C2A);
  float* c1B = (float*)(ws + WS_C1B);
  float* c2B = (float*)(ws + WS_C2B);
  float* invA = (float*)(ws + WS_INVA);
  float* invB = (float*)(ws + WS_INVB);
  float* vz   = (float*)(ws + WS_VPART);
  int tid = blockIdx.x * blockDim.x + threadIdx.x;
  int stride = gridDim.x * blockDim.x;
  for (int i = tid; i < 32*256; i += stride) {          // WA[k][n] -> waT[n][k]
    int k = i >> 8, n = i & 255;
    waT[n*32 + k] = f2bf(WA[i]);
  }
  for (int i = tid; i < 256*64; i += stride) {          // WB[k][n] -> wbT2[n][k], pad K
    int n = i >> 6, k = i & 63;
    wbT2[i] = (k < 48) ? f2bf(WB[k*256 + n]) : (short)0;
  }
  for (int i = tid; i < 256*256; i += stride) {         // (g*Wback)[k][n] -> [n][k]
    int k = i >> 8, n = i & 255;
    float w = Wback[i];
    w2gA[n*256 + k] = f2bf(gA[k] * w);
    w2gB[n*256 + k] = f2bf(gB[k] * w);
  }
  // c1/c2 partials: 8 k-chunks, one block each, no atomics (fused sums the 8 slots)
  if (blockIdx.x < 8) {
    int kc = blockIdx.x;
    int n = threadIdx.x;
    float a1 = 0.f, a2 = 0.f, b1 = 0.f, b2 = 0.f;
    for (int k = kc*32; k < kc*32 + 32; k++) {
      float w = Wback[k*256 + n];
      a1 += gA[k] * w;  a2 += betaA[k] * w;
      b1 += gB[k] * w;  b2 += betaB[k] * w;
    }
    float bb = (kc == 0) ? bback[n] : 0.0f;
    c1A[kc*256 + n] = a1;
    c2A[kc*256 + n] = a2 + bb;
    c1B[kc*256 + n] = b1;
    c2B[kc*256 + n] = b2 + bb;
  }
  if (tid < 32) invA[tid] = 1.0f / sA[tid];
  if (tid < 48) invB[tid] = 1.0f / sB[tid];
  for (int i = tid; i < 2*NSPLIT*NSEG; i += stride) vz[i] = 0.0f;  // vpart+cpart
}

__global__ __launch_bounds__(256, 3) void fused_kernel(
    const float* __restrict__ featsA, const float* __restrict__ featsB,
    const float* __restrict__ mA, const float* __restrict__ mB,
    const float* __restrict__ bA, const float* __restrict__ bB,
    const float* __restrict__ Wv, const int* __restrict__ bidx,
    const char* __restrict__ ws, float* __restrict__ vpart, float* __restrict__ cpart,
    int tilesA, int nA, int nB)
{
  __shared__ __attribute__((aligned(16))) short ztile[64*264];   // h, bf16, stride 264
  __shared__ __attribute__((aligned(16))) float sred[64][4];
  __shared__ __attribute__((aligned(16))) float s2red[64][4];
  __shared__ __attribute__((aligned(16))) float vpw[64][4];

  const int tid  = threadIdx.x;
  const int wave = tid >> 6;
  const int lane = tid & 63;
  const int l15  = lane & 15;
  const int quad = lane >> 4;

  const bool isA = (blockIdx.x < (unsigned)tilesA);
  const int  tb  = isA ? blockIdx.x : (blockIdx.x - tilesA);
  const int  r0  = tb * 64;
  const int  nrows = isA ? nA : nB;
  const int  valid = min(64, nrows - r0);
  const float* feats = isA ? featsA : featsB;
  const float* meanp = isA ? mA : mB;
  const float* invp  = (const float*)(ws + (isA ? WS_INVA : WS_INVB));
  const float* biasp = isA ? bA : bB;
  const short* weT   = (const short*)(ws + (isA ? WS_WAT : WS_WBT2));
  const short* w2gT  = (const short*)(ws + (isA ? WS_W2GA : WS_W2GB));
  const float* c1p   = (const float*)(ws + (isA ? WS_C1A : WS_C1B));
  const float* c2p   = (const float*)(ws + (isA ? WS_C2A : WS_C2B));
  const int f       = isA ? 32 : 48;
  const int kstride = isA ? 32 : 64;
  const int ksteps  = isA ? 1 : 2;

  // per-lane column constants (cols 64*wave + 16*nt + l15); c1/c2 summed from 8 partials
  float b1v[4], c1v[4], c2v[4], wvv[4];
  #pragma unroll
  for (int nt = 0; nt < 4; nt++) {
    int col = 64*wave + 16*nt + l15;
    b1v[nt] = biasp[col];
    wvv[nt] = Wv[col];
    float c1 = 0.f, c2 = 0.f;
    #pragma unroll
    for (int j = 0; j < 8; j++) {
      c1 += c1p[j*256 + col];
      c2 += c2p[j*256 + col];
    }
    c1v[nt] = c1;
    c2v[nt] = c2;
  }

  // ---- GEMM1: h = relu(norm(feats) @ W1 + b1), A-frags straight from global ----
  floatx4 acc1[4][4];
  #pragma unroll
  for (int mt = 0; mt < 4; mt++)
    #pragma unroll
    for (int nt = 0; nt < 4; nt++)
      acc1[mt][nt] = 0.0f;

  for (int kk = 0; kk < ksteps; kk++) {
    const int k0 = kk*32 + quad*8;
    const bool kvalid = (k0 < f);
    floatx4 mv0 = {0,0,0,0}, mv1 = {0,0,0,0}, iv0 = {1,1,1,1}, iv1 = {1,1,1,1};
    if (kvalid) {
      mv0 = *(const floatx4*)(meanp + k0);  mv1 = *(const floatx4*)(meanp + k0 + 4);
      iv0 = *(const floatx4*)(invp + k0);   iv1 = *(const floatx4*)(invp + k0 + 4);
    }
    short8 af[4];
    #pragma unroll
    for (int mt = 0; mt < 4; mt++) {
      short8 a = {0,0,0,0,0,0,0,0};
      int row = 16*mt + l15;
      if (kvalid && row < valid) {
        const float* fp = feats + (size_t)(r0 + row) * f + k0;
        floatx4 x0 = *(const floatx4*)fp;
        floatx4 x1 = *(const floatx4*)(fp + 4);
        #pragma unroll
        for (int e = 0; e < 4; e++) {
          float h0 = (x0[e] - mv0[e]) * iv0[e];
          h0 = fminf(fmaxf(h0, -5.0f), 5.0f);
          a[e] = f2bf(h0);
          float h1 = (x1[e] - mv1[e]) * iv1[e];
          h1 = fminf(fmaxf(h1, -5.0f), 5.0f);
          a[4+e] = f2bf(h1);
        }
      }
      af[mt] = a;
    }
    short8 bfw[4];
    #pragma unroll
    for (int nt = 0; nt < 4; nt++)
      bfw[nt] = *(const short8*)(weT + (size_t)(64*wave + 16*nt + l15) * kstride + kk*32 + quad*8);
    #pragma unroll
    for (int mt = 0; mt < 4; mt++)
      #pragma unroll
      for (int nt = 0; nt < 4; nt++)
        acc1[mt][nt] = __builtin_amdgcn_mfma_f32_16x16x32_bf16(af[mt], bfw[nt], acc1[mt][nt], 0, 0, 0);
  }

  // ---- epilogue1: h=relu(.+b1) -> ztile (bf16) + stats (s, s2) from registers ----
  float sacc[4][4], s2acc[4][4];
  #pragma unroll
  for (int mt = 0; mt < 4; mt++)
    #pragma unroll
    for (int r = 0; r < 4; r++) { sacc[mt][r] = 0.f; s2acc[mt][r] = 0.f; }

  #pragma unroll
  for (int nt = 0; nt < 4; nt++) {
    int col = 64*wave + 16*nt + l15;
    #pragma unroll
    for (int mt = 0; mt < 4; mt++)
      #pragma unroll
      for (int r = 0; r < 4; r++) {
        float h = fmaxf(acc1[mt][nt][r] + b1v[nt], 0.0f);
        sacc[mt][r] += h;
        s2acc[mt][r] = fmaf(h, h, s2acc[mt][r]);
        ztile[(16*mt + 4*quad + r)*264 + col] = f2bf(h);
      }
  }
  // reduce stats over the 16 l15 lanes; C-layout rows == epilogue2 rows, no redistribution
  #pragma unroll
  for (int mt = 0; mt < 4; mt++)
    #pragma unroll
    for (int r = 0; r < 4; r++) {
      float s = sacc[mt][r], s2 = s2acc[mt][r];
      s  += __shfl_xor(s, 1, 64);  s2 += __shfl_xor(s2, 1, 64);
      s  += __shfl_xor(s, 2, 64);  s2 += __shfl_xor(s2, 2, 64);
      s  += __shfl_xor(s, 4, 64);  s2 += __shfl_xor(s2, 4, 64);
      s  += __shfl_xor(s, 8, 64);  s2 += __shfl_xor(s2, 8, 64);
      if (l15 == 0) {
        int row = 16*mt + 4*quad + r;
        sred[row][wave] = s;
        s2red[row][wave] = s2;
      }
    }
  __syncthreads();

  // ---- per-row LN scalars for MY epilogue2 rows ----
  float rsv[4][4], mrsv[4][4];
  #pragma unroll
  for (int mt = 0; mt < 4; mt++)
    #pragma unroll
    for (int r = 0; r < 4; r++) {
      int row = 16*mt + 4*quad + r;
      floatx4 sv  = *(const floatx4*)sred[row];
      floatx4 s2v = *(const floatx4*)s2red[row];
      float s  = sv[0] + sv[1] + sv[2] + sv[3];
      float s2 = s2v[0] + s2v[1] + s2v[2] + s2v[3];
      float mu  = s * (1.0f/256.0f);
      float var = fmaxf(s2 * (1.0f/256.0f) - mu*mu, 0.0f);
      float rs  = rsqrtf(var + 1e-5f);
      rsv[mt][r]  = rs;
      mrsv[mt][r] = mu * rs;
    }

  // ---- GEMM2: q = h @ (g*Wback), K=256 ----
  floatx4 acc2[4][4];
  #pragma unroll
  for (int mt = 0; mt < 4; mt++)
    #pragma unroll
    for (int nt = 0; nt < 4; nt++)
      acc2[mt][nt] = 0.0f;

  #pragma unroll
  for (int kk = 0; kk < 8; kk++) {
    short8 bf[4];
    #pragma unroll
    for (int nt = 0; nt < 4; nt++)
      bf[nt] = *(const short8*)(w2gT + (size_t)(64*wave + 16*nt + l15)*256 + kk*32 + quad*8);
    short8 af[4];
    #pragma unroll
    for (int mt = 0; mt < 4; mt++)
      af[mt] = *(const short8*)(ztile + (16*mt + l15)*264 + kk*32 + quad*8);
    #pragma unroll
    for (int mt = 0; mt < 4; mt++)
      #pragma unroll
      for (int nt = 0; nt < 4; nt++)
        acc2[mt][nt] = __builtin_amdgcn_mfma_f32_16x16x32_bf16(af[mt], bf[nt], acc2[mt][nt], 0, 0, 0);
  }

  // ---- epilogue2: y = relu(rs*q - mu*rs*c1 + c2); v = y . Wv ----
  #pragma unroll
  for (int mt = 0; mt < 4; mt++)
    #pragma unroll
    for (int r = 0; r < 4; r++) {
      float rs = rsv[mt][r], mrs = mrsv[mt][r];
      float pv = 0.0f;
      #pragma unroll
      for (int nt = 0; nt < 4; nt++) {
        float t = fmaf(-mrs, c1v[nt], c2v[nt]);
        float y = fmaf(rs, acc2[mt][nt][r], t);
        y = fmaxf(y, 0.0f);
        pv = fmaf(y, wvv[nt], pv);
      }
      pv += __shfl_xor(pv, 1, 64);
      pv += __shfl_xor(pv, 2, 64);
      pv += __shfl_xor(pv, 4, 64);
      pv += __shfl_xor(pv, 8, 64);
      if (l15 == 0) vpw[16*mt + 4*quad + r][wave] = pv;
    }
  __syncthreads();

  // ---- scatter ----
  if (tid < valid) {
    floatx4 vv = *(const floatx4*)vpw[tid];
    float v = vv[0] + vv[1] + vv[2] + vv[3];
    int g = (isA ? r0 : (nA + r0)) + tid;
    int seg = bidx[g];
    int split = blockIdx.x & (NSPLIT - 1);
    atomicAdd(&vpart[split*NSEG + seg], v);
    atomicAdd(&cpart[split*NSEG + seg], 1.0f);
  }
}

__global__ void final_kernel(const float* __restrict__ vpart, const float* __restrict__ cpart,
                             const float* __restrict__ bv, float* __restrict__ out, int nseg) {
  int s = blockIdx.x * blockDim.x + threadIdx.x;
  if (s < nseg) {
    float a = 0.0f, c = 0.0f;
    #pragma unroll 8
    for (int i = 0; i < NSPLIT; i++) { a += vpart[i*NSEG + s]; c += cpart[i*NSEG + s]; }
    out[s] = a / fmaxf(c, 1.0f) + bv[0];
  }
}

extern "C" void kernel_launch(void* const* d_in, const int* in_sizes, int n_in,
                              void* d_out, int out_size, void* d_ws, size_t ws_size,
                              hipStream_t stream) {
  const float* featsA = (const float*)d_in[0];
  const float* featsB = (const float*)d_in[1];
  const float* mA     = (const float*)d_in[2];
  const float* sA     = (const float*)d_in[3];
  const float* mB     = (const float*)d_in[4];
  const float* sB     = (const float*)d_in[5];
  const float* WA     = (const float*)d_in[6];
  const float* bA     = (const float*)d_in[7];
  const float* gA     = (const float*)d_in[8];
  const float* betaA  = (const float*)d_in[9];
  const float* WB     = (const float*)d_in[10];
  const float* bB     = (const float*)d_in[11];
  const float* gB     = (const float*)d_in[12];
  const float* betaB  = (const float*)d_in[13];
  const float* Wback  = (const float*)d_in[14];
  const float* bback  = (const float*)d_in[15];
  const float* Wv     = (const float*)d_in[16];
  const float* bv     = (const float*)d_in[17];
  const int*   bidx   = (const int*)d_in[18];

  const int nA = in_sizes[0] / 32;
  const int nB = in_sizes[1] / 48;
  char* ws = (char*)d_ws;
  float* vpart = (float*)(ws + WS_VPART);
  float* cpart = (float*)(ws + WS_CPART);
  float* out = (float*)d_out;

  prep_kernel<<<256, 256, 0, stream>>>(WA, WB, Wback, gA, betaA, gB, betaB,
                                       bback, sA, sB, ws);

  const int tilesA = (nA + 63) / 64;
  const int tilesB = (nB + 63) / 64;
  fused_kernel<<<tilesA + tilesB, 256, 0, stream>>>(
      featsA, featsB, mA, mB, bA, bB, Wv, bidx, ws, vpart, cpart, tilesA, nA, nB);

  final_kernel<<<(out_size + 255) / 256, 256, 0, stream>>>(vpart, cpart, bv, out, out_size);
}

// Round 5
// 485.147 us; speedup vs baseline: 1.1945x; 1.1945x over previous
//
#include <hip/hip_runtime.h>

#define NSEG 512
#define NSPLIT 16

typedef __attribute__((ext_vector_type(8))) short short8;
typedef __attribute__((ext_vector_type(4))) float floatx4;

// ws layout (bytes), all 16B-aligned, total 414016 <= proven 446784
#define WS_WAT   0        // short [256][32]   WA^T
#define WS_WBT2  16384    // short [256][64]   WB^T (K padded 48->64 w/ zeros)
#define WS_W2GA  49152    // short [256][256]  (gA*Wback)^T
#define WS_W2GB  180224   // short [256][256]  (gB*Wback)^T
#define WS_C1A   311296   // float[8][256] partials (k-chunk j)
#define WS_C2A   319488   // float[8][256] partials (+bback in j=0)
#define WS_C1B   327680   // float[8][256]
#define WS_C2B   335872   // float[8][256]
#define WS_INVA  344064   // float[32]  1/stdA
#define WS_INVB  344192   // float[48]  1/stdB
#define WS_VPART 344384   // float [NSPLIT][NSEG]
#define WS_CPART 377152   // float [NSPLIT][NSEG]
#define WS_C1AF  409920   // float[256] finalized
#define WS_C2AF  410944
#define WS_C1BF  411968
#define WS_C2BF  412992
// end 414016

__device__ __forceinline__ short f2bf(float f) {  // RNE
  unsigned u = __builtin_bit_cast(unsigned, f);
  u += 0x7FFFu + ((u >> 16) & 1u);
  return (short)(u >> 16);
}

__global__ void prep_kernel(const float* __restrict__ WA, const float* __restrict__ WB,
                            const float* __restrict__ Wback,
                            const float* __restrict__ gA, const float* __restrict__ betaA,
                            const float* __restrict__ gB, const float* __restrict__ betaB,
                            const float* __restrict__ bback,
                            const float* __restrict__ sA, const float* __restrict__ sB,
                            char* __restrict__ ws) {
  short* waT  = (short*)(ws + WS_WAT);
  short* wbT2 = (short*)(ws + WS_WBT2);
  short* w2gA = (short*)(ws + WS_W2GA);
  short* w2gB = (short*)(ws + WS_W2GB);
  float* c1A = (float*)(ws + WS_C1A);
  float* c2A = (float*)(ws + WS_C2A);
  float* c1B = (float*)(ws + WS_C1B);
  float* c2B = (float*)(ws + WS_C2B);
  float* invA = (float*)(ws + WS_INVA);
  float* invB = (float*)(ws + WS_INVB);
  float* vz   = (float*)(ws + WS_VPART);
  int tid = blockIdx.x * blockDim.x + threadIdx.x;
  int stride = gridDim.x * blockDim.x;
  for (int i = tid; i < 32*256; i += stride) {          // WA[k][n] -> waT[n][k]
    int k = i >> 8, n = i & 255;
    waT[n*32 + k] = f2bf(WA[i]);
  }
  for (int i = tid; i < 256*64; i += stride) {          // WB[k][n] -> wbT2[n][k], pad K
    int n = i >> 6, k = i & 63;
    wbT2[i] = (k < 48) ? f2bf(WB[k*256 + n]) : (short)0;
  }
  for (int i = tid; i < 256*256; i += stride) {         // (g*Wback)[k][n] -> [n][k]
    int k = i >> 8, n = i & 255;
    float w = Wback[i];
    w2gA[n*256 + k] = f2bf(gA[k] * w);
    w2gB[n*256 + k] = f2bf(gB[k] * w);
  }
  // c1/c2 partials: 8 k-chunks, one block each, no atomics (prep2 sums the 8 slots)
  if (blockIdx.x < 8) {
    int kc = blockIdx.x;
    int n = threadIdx.x;
    float a1 = 0.f, a2 = 0.f, b1 = 0.f, b2 = 0.f;
    for (int k = kc*32; k < kc*32 + 32; k++) {
      float w = Wback[k*256 + n];
      a1 += gA[k] * w;  a2 += betaA[k] * w;
      b1 += gB[k] * w;  b2 += betaB[k] * w;
    }
    float bb = (kc == 0) ? bback[n] : 0.0f;
    c1A[kc*256 + n] = a1;
    c2A[kc*256 + n] = a2 + bb;
    c1B[kc*256 + n] = b1;
    c2B[kc*256 + n] = b2 + bb;
  }
  if (tid < 32) invA[tid] = 1.0f / sA[tid];
  if (tid < 48) invB[tid] = 1.0f / sB[tid];
  for (int i = tid; i < 2*NSPLIT*NSEG; i += stride) vz[i] = 0.0f;  // vpart+cpart
}

// finalize c1/c2 (sum the 8 partials once, instead of in every fused thread)
__global__ void prep2_kernel(char* __restrict__ ws) {
  int n = threadIdx.x;  // 256 threads, 1 block
  const float* c1A = (const float*)(ws + WS_C1A);
  const float* c2A = (const float*)(ws + WS_C2A);
  const float* c1B = (const float*)(ws + WS_C1B);
  const float* c2B = (const float*)(ws + WS_C2B);
  float a1 = 0.f, a2 = 0.f, b1 = 0.f, b2 = 0.f;
  #pragma unroll
  for (int j = 0; j < 8; j++) {
    a1 += c1A[j*256 + n];  a2 += c2A[j*256 + n];
    b1 += c1B[j*256 + n];  b2 += c2B[j*256 + n];
  }
  ((float*)(ws + WS_C1AF))[n] = a1;
  ((float*)(ws + WS_C2AF))[n] = a2;
  ((float*)(ws + WS_C1BF))[n] = b1;
  ((float*)(ws + WS_C2BF))[n] = b2;
}

// 32-row tile, 4 waves x 64 cols. Register peak ~115 -> fits 4 waves/EU without spill.
__global__ __launch_bounds__(256, 4) void fused_kernel(
    const float* __restrict__ featsA, const float* __restrict__ featsB,
    const float* __restrict__ mA, const float* __restrict__ mB,
    const float* __restrict__ bA, const float* __restrict__ bB,
    const float* __restrict__ Wv, const int* __restrict__ bidx,
    const char* __restrict__ ws, float* __restrict__ vpart, float* __restrict__ cpart,
    int tilesA, int nA, int nB)
{
  __shared__ __attribute__((aligned(16))) short ztile[32*264];   // h, bf16, stride 264
  __shared__ __attribute__((aligned(16))) float sred[32][4];
  __shared__ __attribute__((aligned(16))) float s2red[32][4];
  __shared__ __attribute__((aligned(16))) float vpw[32][4];

  const int tid  = threadIdx.x;
  const int wave = tid >> 6;
  const int lane = tid & 63;
  const int l15  = lane & 15;
  const int quad = lane >> 4;

  const bool isA = (blockIdx.x < (unsigned)tilesA);
  const int  tb  = isA ? blockIdx.x : (blockIdx.x - tilesA);
  const int  r0  = tb * 32;
  const int  nrows = isA ? nA : nB;
  const int  valid = min(32, nrows - r0);
  const float* feats = isA ? featsA : featsB;
  const float* meanp = isA ? mA : mB;
  const float* invp  = (const float*)(ws + (isA ? WS_INVA : WS_INVB));
  const float* biasp = isA ? bA : bB;
  const short* weT   = (const short*)(ws + (isA ? WS_WAT : WS_WBT2));
  const short* w2gT  = (const short*)(ws + (isA ? WS_W2GA : WS_W2GB));
  const float* c1p   = (const float*)(ws + (isA ? WS_C1AF : WS_C1BF));
  const float* c2p   = (const float*)(ws + (isA ? WS_C2AF : WS_C2BF));
  const int f       = isA ? 32 : 48;
  const int kstride = isA ? 32 : 64;
  const int ksteps  = isA ? 1 : 2;

  // per-lane column constants (cols 64*wave + 16*nt + l15)
  float b1v[4], c1v[4], c2v[4], wvv[4];
  #pragma unroll
  for (int nt = 0; nt < 4; nt++) {
    int col = 64*wave + 16*nt + l15;
    b1v[nt] = biasp[col];
    wvv[nt] = Wv[col];
    c1v[nt] = c1p[col];
    c2v[nt] = c2p[col];
  }

  // ---- GEMM1: h = relu(norm(feats) @ W1 + b1), A-frags straight from global ----
  floatx4 acc1[2][4];
  #pragma unroll
  for (int mt = 0; mt < 2; mt++)
    #pragma unroll
    for (int nt = 0; nt < 4; nt++)
      acc1[mt][nt] = 0.0f;

  for (int kk = 0; kk < ksteps; kk++) {
    const int k0 = kk*32 + quad*8;
    const bool kvalid = (k0 < f);
    floatx4 mv0 = {0,0,0,0}, mv1 = {0,0,0,0}, iv0 = {1,1,1,1}, iv1 = {1,1,1,1};
    if (kvalid) {
      mv0 = *(const floatx4*)(meanp + k0);  mv1 = *(const floatx4*)(meanp + k0 + 4);
      iv0 = *(const floatx4*)(invp + k0);   iv1 = *(const floatx4*)(invp + k0 + 4);
    }
    short8 af[2];
    #pragma unroll
    for (int mt = 0; mt < 2; mt++) {
      short8 a = {0,0,0,0,0,0,0,0};
      int row = 16*mt + l15;
      if (kvalid && row < valid) {
        const float* fp = feats + (size_t)(r0 + row) * f + k0;
        floatx4 x0 = *(const floatx4*)fp;
        floatx4 x1 = *(const floatx4*)(fp + 4);
        #pragma unroll
        for (int e = 0; e < 4; e++) {
          float h0 = (x0[e] - mv0[e]) * iv0[e];
          h0 = fminf(fmaxf(h0, -5.0f), 5.0f);
          a[e] = f2bf(h0);
          float h1 = (x1[e] - mv1[e]) * iv1[e];
          h1 = fminf(fmaxf(h1, -5.0f), 5.0f);
          a[4+e] = f2bf(h1);
        }
      }
      af[mt] = a;
    }
    short8 bfw[4];
    #pragma unroll
    for (int nt = 0; nt < 4; nt++)
      bfw[nt] = *(const short8*)(weT + (size_t)(64*wave + 16*nt + l15) * kstride + kk*32 + quad*8);
    #pragma unroll
    for (int mt = 0; mt < 2; mt++)
      #pragma unroll
      for (int nt = 0; nt < 4; nt++)
        acc1[mt][nt] = __builtin_amdgcn_mfma_f32_16x16x32_bf16(af[mt], bfw[nt], acc1[mt][nt], 0, 0, 0);
  }

  // ---- epilogue1: h=relu(.+b1) -> ztile (bf16) + stats (s, s2) from registers ----
  float sacc[2][4], s2acc[2][4];
  #pragma unroll
  for (int mt = 0; mt < 2; mt++)
    #pragma unroll
    for (int r = 0; r < 4; r++) { sacc[mt][r] = 0.f; s2acc[mt][r] = 0.f; }

  #pragma unroll
  for (int nt = 0; nt < 4; nt++) {
    int col = 64*wave + 16*nt + l15;
    #pragma unroll
    for (int mt = 0; mt < 2; mt++)
      #pragma unroll
      for (int r = 0; r < 4; r++) {
        float h = fmaxf(acc1[mt][nt][r] + b1v[nt], 0.0f);
        sacc[mt][r] += h;
        s2acc[mt][r] = fmaf(h, h, s2acc[mt][r]);
        ztile[(16*mt + 4*quad + r)*264 + col] = f2bf(h);
      }
  }
  // reduce stats over the 16 l15 lanes; C-layout rows == epilogue2 rows
  #pragma unroll
  for (int mt = 0; mt < 2; mt++)
    #pragma unroll
    for (int r = 0; r < 4; r++) {
      float s = sacc[mt][r], s2 = s2acc[mt][r];
      s  += __shfl_xor(s, 1, 64);  s2 += __shfl_xor(s2, 1, 64);
      s  += __shfl_xor(s, 2, 64);  s2 += __shfl_xor(s2, 2, 64);
      s  += __shfl_xor(s, 4, 64);  s2 += __shfl_xor(s2, 4, 64);
      s  += __shfl_xor(s, 8, 64);  s2 += __shfl_xor(s2, 8, 64);
      if (l15 == 0) {
        int row = 16*mt + 4*quad + r;
        sred[row][wave] = s;
        s2red[row][wave] = s2;
      }
    }
  __syncthreads();

  // ---- per-row LN scalars for MY epilogue2 rows ----
  float rsv[2][4], mrsv[2][4];
  #pragma unroll
  for (int mt = 0; mt < 2; mt++)
    #pragma unroll
    for (int r = 0; r < 4; r++) {
      int row = 16*mt + 4*quad + r;
      floatx4 sv  = *(const floatx4*)sred[row];
      floatx4 s2v = *(const floatx4*)s2red[row];
      float s  = sv[0] + sv[1] + sv[2] + sv[3];
      float s2 = s2v[0] + s2v[1] + s2v[2] + s2v[3];
      float mu  = s * (1.0f/256.0f);
      float var = fmaxf(s2 * (1.0f/256.0f) - mu*mu, 0.0f);
      float rs  = rsqrtf(var + 1e-5f);
      rsv[mt][r]  = rs;
      mrsv[mt][r] = mu * rs;
    }

  // ---- GEMM2: q = h @ (g*Wback), K=256 ----
  floatx4 acc2[2][4];
  #pragma unroll
  for (int mt = 0; mt < 2; mt++)
    #pragma unroll
    for (int nt = 0; nt < 4; nt++)
      acc2[mt][nt] = 0.0f;

  #pragma unroll
  for (int kk = 0; kk < 8; kk++) {
    short8 bf[4];
    #pragma unroll
    for (int nt = 0; nt < 4; nt++)
      bf[nt] = *(const short8*)(w2gT + (size_t)(64*wave + 16*nt + l15)*256 + kk*32 + quad*8);
    short8 af[2];
    #pragma unroll
    for (int mt = 0; mt < 2; mt++)
      af[mt] = *(const short8*)(ztile + (16*mt + l15)*264 + kk*32 + quad*8);
    #pragma unroll
    for (int mt = 0; mt < 2; mt++)
      #pragma unroll
      for (int nt = 0; nt < 4; nt++)
        acc2[mt][nt] = __builtin_amdgcn_mfma_f32_16x16x32_bf16(af[mt], bf[nt], acc2[mt][nt], 0, 0, 0);
  }

  // ---- epilogue2: y = relu(rs*q - mu*rs*c1 + c2); v = y . Wv ----
  #pragma unroll
  for (int mt = 0; mt < 2; mt++)
    #pragma unroll
    for (int r = 0; r < 4; r++) {
      float rs = rsv[mt][r], mrs = mrsv[mt][r];
      float pv = 0.0f;
      #pragma unroll
      for (int nt = 0; nt < 4; nt++) {
        float t = fmaf(-mrs, c1v[nt], c2v[nt]);
        float y = fmaf(rs, acc2[mt][nt][r], t);
        y = fmaxf(y, 0.0f);
        pv = fmaf(y, wvv[nt], pv);
      }
      pv += __shfl_xor(pv, 1, 64);
      pv += __shfl_xor(pv, 2, 64);
      pv += __shfl_xor(pv, 4, 64);
      pv += __shfl_xor(pv, 8, 64);
      if (l15 == 0) vpw[16*mt + 4*quad + r][wave] = pv;
    }
  __syncthreads();

  // ---- scatter ----
  if (tid < valid) {
    floatx4 vv = *(const floatx4*)vpw[tid];
    float v = vv[0] + vv[1] + vv[2] + vv[3];
    int g = (isA ? r0 : (nA + r0)) + tid;
    int seg = bidx[g];
    int split = blockIdx.x & (NSPLIT - 1);
    atomicAdd(&vpart[split*NSEG + seg], v);
    atomicAdd(&cpart[split*NSEG + seg], 1.0f);
  }
}

__global__ void final_kernel(const float* __restrict__ vpart, const float* __restrict__ cpart,
                             const float* __restrict__ bv, float* __restrict__ out, int nseg) {
  int s = blockIdx.x * blockDim.x + threadIdx.x;
  if (s < nseg) {
    float a = 0.0f, c = 0.0f;
    #pragma unroll 8
    for (int i = 0; i < NSPLIT; i++) { a += vpart[i*NSEG + s]; c += cpart[i*NSEG + s]; }
    out[s] = a / fmaxf(c, 1.0f) + bv[0];
  }
}

extern "C" void kernel_launch(void* const* d_in, const int* in_sizes, int n_in,
                              void* d_out, int out_size, void* d_ws, size_t ws_size,
                              hipStream_t stream) {
  const float* featsA = (const float*)d_in[0];
  const float* featsB = (const float*)d_in[1];
  const float* mA     = (const float*)d_in[2];
  const float* sA     = (const float*)d_in[3];
  const float* mB     = (const float*)d_in[4];
  const float* sB     = (const float*)d_in[5];
  const float* WA     = (const float*)d_in[6];
  const float* bA     = (const float*)d_in[7];
  const float* gA     = (const float*)d_in[8];
  const float* betaA  = (const float*)d_in[9];
  const float* WB     = (const float*)d_in[10];
  const float* bB     = (const float*)d_in[11];
  const float* gB     = (const float*)d_in[12];
  const float* betaB  = (const float*)d_in[13];
  const float* Wback  = (const float*)d_in[14];
  const float* bback  = (const float*)d_in[15];
  const float* Wv     = (const float*)d_in[16];
  const float* bv     = (const float*)d_in[17];
  const int*   bidx   = (const int*)d_in[18];

  const int nA = in_sizes[0] / 32;
  const int nB = in_sizes[1] / 48;
  char* ws = (char*)d_ws;
  float* vpart = (float*)(ws + WS_VPART);
  float* cpart = (float*)(ws + WS_CPART);
  float* out = (float*)d_out;

  prep_kernel<<<256, 256, 0, stream>>>(WA, WB, Wback, gA, betaA, gB, betaB,
                                       bback, sA, sB, ws);
  prep2_kernel<<<1, 256, 0, stream>>>(ws);

  const int tilesA = (nA + 31) / 32;
  const int tilesB = (nB + 31) / 32;
  fused_kernel<<<tilesA + tilesB, 256, 0, stream>>>(
      featsA, featsB, mA, mB, bA, bB, Wv, bidx, ws, vpart, cpart, tilesA, nA, nB);

  final_kernel<<<(out_size + 255) / 256, 256, 0, stream>>>(vpart, cpart, bv, out, out_size);
}